// Round 1
// 418.192 us; speedup vs baseline: 1.5480x; 1.5480x over previous
//
#include <hip/hip_runtime.h>

#define Mc 512
#define Nc 1024
#define WRc 16
#define Bc 4096

// c2v state indexed by step-slot s = t mod 512 (cn_order is a per-sweep
// permutation reused identically every sweep). Layout [s][b][j]; slot offset
// uniform (s<<16 elements), lane part (b*16+j) loop-invariant. Sweep 0 never
// reads it -> no init needed (idempotent across launches).
__device__ float g_c2v[(size_t)Mc * Bc * WRc];

#define DPPI(old, src, ctrl) \
  __builtin_amdgcn_update_dpp((old), (src), (ctrl), 0xF, 0xF, false)

static __device__ __forceinline__ int imin(int a, int b) { return a < b ? a : b; }

// One decoder step. k: static unroll index (t&7). ZEROC: sweep 0, c2v==0.
// LOADC: issue depth-8 c2v prefetch.
// Chain design: the gather for step t+1 (vsp) is issued BEFORE the scatter of
// step t (DS pipe is in-order per wave -> reads pre-scatter values). That is
// correct unless row t+1 overlaps row t, which is a STATIC property of H
// precomputed into bit15 of hp (wave-uniform). Only flagged steps (~22%) pay
// the post-scatter LDS round-trip via re-read.
#define STEP(k, ZEROC, LOADC)                                                 \
  {                                                                           \
    const int t = tb + (k);                                                   \
    const int ia = idx_nxt & 1023;                                            \
    const float vsp = vn[ia][g]; /* early speculative gather for t+1 */       \
    const float v2c = (ZEROC) ? v : (v - c2vf[k]);                            \
    const int vb = __float_as_int(v2c);                                       \
    const int ab = vb & 0x7FFFFFFF;                                           \
    const unsigned long long bal = __ballot(v2c < 0.0f);                      \
    int p = ab, s2 = ab;                                                      \
    p = imin(p, DPPI(0x7FFFFFFF, p, 0x111)); /* row_shr:1 */                  \
    p = imin(p, DPPI(0x7FFFFFFF, p, 0x112));                                  \
    p = imin(p, DPPI(0x7FFFFFFF, p, 0x114));                                  \
    p = imin(p, DPPI(0x7FFFFFFF, p, 0x118));                                  \
    s2 = imin(s2, DPPI(0x7FFFFFFF, s2, 0x101)); /* row_shl:1 */               \
    s2 = imin(s2, DPPI(0x7FFFFFFF, s2, 0x102));                               \
    s2 = imin(s2, DPPI(0x7FFFFFFF, s2, 0x104));                               \
    s2 = imin(s2, DPPI(0x7FFFFFFF, s2, 0x108));                               \
    const int loo = imin(DPPI(0x7FFFFFFF, p, 0x111),                          \
                         DPPI(0x7FFFFFFF, s2, 0x101));                        \
    const unsigned m16 = ((unsigned)(bal >> sh)) & 0xFFFFu;                   \
    const unsigned negb = (((unsigned)__popc(m16) << 31) ^                    \
                           ((unsigned)vb & 0x80000000u));                     \
    const int ncb = imin(0x41A00000 /*20.0f*/, loo) | (int)negb;              \
    const float ncf = __int_as_float(ncb);                                    \
    vn[idx_cur][g] = v2c + ncf; /* scatter (step t) */                        \
    cptr[(size_t)(t & (Mc - 1)) << 16] = ncf;                                 \
    if (LOADC) c2vf[k] = cptr[(size_t)((t + 8) & (Mc - 1)) << 16];            \
    v = vsp;                                                                  \
    if (__builtin_amdgcn_readfirstlane(idx_nxt) & 0x8000)                     \
      v = vn[ia][g]; /* row t+1 overlaps row t: re-read after scatter */      \
    idx_cur = ia;                                                             \
    idx_nxt = idx_f2;                                                         \
    idx_f2 = hp[((t + 3) & (Mc - 1)) * WRc + j];                              \
  }

#define STEP8(Z, L)                                                \
  STEP(0, Z, L) STEP(1, Z, L) STEP(2, Z, L) STEP(3, Z, L)          \
  STEP(4, Z, L) STEP(5, Z, L) STEP(6, Z, L) STEP(7, Z, L)

__global__ __launch_bounds__(64) void ldpc_kernel(
    const float* __restrict__ llr, const int* __restrict__ H,
    const int* __restrict__ iters_p, const int* __restrict__ cn_order,
    float* __restrict__ out) {
  const int tid = threadIdx.x;
  const int g = tid >> 4;    // batch sub-slot within wave (0..3)
  const int j = tid & 15;    // edge position within check node
  const int sh = tid & 48;   // g*16, ballot slice shift
  const int b0 = blockIdx.x * 4;
  const int b = b0 + g;

  // [n][g] layout: bank = (4n+g)%32 -> the 4 groups occupy disjoint bank
  // quads (old [4][1024] layout forced a structural 4-way conflict).
  __shared__ float vn[Nc][4];              // 16 KB
  __shared__ unsigned short hp[Mc * WRc];  // 16 KB, bit15 = overlap(s, s-1)

  for (int i = tid; i < 4 * Nc; i += 64) {
    const int gg = i >> 10, n = i & (Nc - 1);
    vn[n][gg] = llr[(size_t)(b0 + gg) * Nc + n];
  }
  for (int i = tid; i < Mc * WRc; i += 64)
    hp[i] = (unsigned short)H[cn_order[i >> 4] * WRc + (i & 15)];
  __syncthreads();

  // Precompute per-row overlap flags: bit15 of every entry of row s marks
  // overlap(row s, row s-1 mod 512) — i.e. at step t, whether the early
  // gather of row t+1 must be redone after row t's scatter. One-time (~3 us).
  {
    unsigned ov = 0;
    unsigned short prev[16], cur[16];
    const int s0 = tid * 8;
    const int sp0 = (s0 + Mc - 1) & (Mc - 1);
#pragma unroll
    for (int a = 0; a < 16; ++a) prev[a] = hp[sp0 * WRc + a];
    for (int r = 0; r < 8; ++r) {
      const int s = s0 + r;
#pragma unroll
      for (int a = 0; a < 16; ++a) cur[a] = hp[s * WRc + a];
      bool o = false;
#pragma unroll
      for (int a = 0; a < 16; ++a)
#pragma unroll
        for (int c = 0; c < 16; ++c) o |= (cur[a] == prev[c]);
      ov |= (o ? 1u : 0u) << r;
#pragma unroll
      for (int a = 0; a < 16; ++a) prev[a] = cur[a];
    }
    __syncthreads();
    for (int r = 0; r < 8; ++r)
      if ((ov >> r) & 1u) {
        const int s = tid * 8 + r;
        for (int a = 0; a < 16; ++a) hp[s * WRc + a] |= 0x8000;
      }
    __syncthreads();
  }

  const int T = iters_p[0] * Mc;  // multiple of 8
  float* const cptr = g_c2v + ((size_t)b * WRc + j);

  // ---- pipeline prime ----
  int idx_cur = hp[j] & 1023;
  int idx_nxt = hp[1 * WRc + j];  // keep flag bit
  int idx_f2 = hp[2 * WRc + j];
  float v = vn[idx_cur][g];
  float c2vf[8] = {0, 0, 0, 0, 0, 0, 0, 0};

  // Sweep 0 (c2v == 0, no prefetch) ... bridge (starts prefetch of slots
  // 0..7) ... main sweeps (prefetch depth 8 == one unrolled iteration, so
  // c2vf indices stay static -> registers, not scratch).
  int tb = 0;
  for (; tb < Mc - 8; tb += 8) { STEP8(1, 0) }
  { STEP8(1, 1) }  // tb == 504
  tb = Mc;
  for (; tb < T; tb += 8) { STEP8(0, 1) }

  // Hard decision. Block = one wave: wave-synchronous, no barrier needed.
  for (int i = tid; i < 4 * Nc; i += 64) {
    const int gg = i >> 10, n = i & (Nc - 1);
    out[(size_t)(b0 + gg) * Nc + n] = (vn[n][gg] < 0.0f) ? 1.0f : 0.0f;
  }
}

extern "C" void kernel_launch(void* const* d_in, const int* in_sizes, int n_in,
                              void* d_out, int out_size, void* d_ws, size_t ws_size,
                              hipStream_t stream) {
  const float* llr = (const float*)d_in[0];
  const int* H = (const int*)d_in[1];
  const int* iters_p = (const int*)d_in[2];
  const int* cn_order = (const int*)d_in[3];
  float* out = (float*)d_out;
  ldpc_kernel<<<dim3(Bc / 4), dim3(64), 0, stream>>>(llr, H, iters_p, cn_order, out);
}

// Round 2
// 399.177 us; speedup vs baseline: 1.6218x; 1.0476x over previous
//
#include <hip/hip_runtime.h>

#define Mc 512
#define Nc 1024
#define WRc 16
#define Bc 4096

// c2v state indexed by step-slot s = t mod 512 (cn_order is a per-sweep
// permutation reused identically every sweep). Layout [s][b][j]; slot offset
// uniform (s<<16 elements), lane part (b*16+j) loop-invariant. Sweep 0 never
// reads it -> no init needed (idempotent across launches).
__device__ float g_c2v[(size_t)Mc * Bc * WRc];

#define DPPI(old, src, ctrl) \
  __builtin_amdgcn_update_dpp((old), (src), (ctrl), 0xF, 0xF, false)

static __device__ __forceinline__ int imin(int a, int b) { return a < b ? a : b; }

// Min-sum check-node message for one row: exclusive leave-one-out |min| via
// prefix/suffix DPP int-min scans (row-scoped, 16-lane groups) + sign parity
// via ballot. Proven correct in previous rounds; two concurrent calls have
// fully independent chains -> the scheduler interleaves them (ILP 2).
static __device__ __forceinline__ float check_msg(float v2c, int sh) {
  const int INFB = 0x7FFFFFFF;
  const int vb = __float_as_int(v2c);
  const int ab = vb & 0x7FFFFFFF;
  const unsigned long long bal = __ballot(v2c < 0.0f);
  int p = ab;
  p = imin(p, DPPI(INFB, p, 0x111));  // row_shr:1
  p = imin(p, DPPI(INFB, p, 0x112));
  p = imin(p, DPPI(INFB, p, 0x114));
  p = imin(p, DPPI(INFB, p, 0x118));
  int s2 = ab;
  s2 = imin(s2, DPPI(INFB, s2, 0x101));  // row_shl:1
  s2 = imin(s2, DPPI(INFB, s2, 0x102));
  s2 = imin(s2, DPPI(INFB, s2, 0x104));
  s2 = imin(s2, DPPI(INFB, s2, 0x108));
  const int loo = imin(DPPI(INFB, p, 0x111), DPPI(INFB, s2, 0x101));
  const unsigned m16 = ((unsigned)(bal >> sh)) & 0xFFFFu;
  const unsigned negb =
      ((unsigned)__popc(m16) << 31) ^ ((unsigned)vb & 0x80000000u);
  return __int_as_float(imin(0x41A00000 /*20.0f*/, loo) | (int)negb);
}

// One PAIR of consecutive rows (tA = tb+2k, tB = tA+1).
// Disjoint consecutive rows commute exactly (touch disjoint vn columns and
// disjoint c2v slots), so both scans run concurrently -> 2 independent
// dependency chains fill each other's bubbles. Overlapping pairs (bit15 of
// row tB's hp entries, ~22%) serialize: A fully, re-gather B, B fully.
// Gathers for the NEXT pair are issued after this pair's scatters (program
// order, LDS in-order) -> the only speculation hazard is intra-pair.
#define PAIR(k, ZEROC, LOADC)                                              \
  {                                                                        \
    const int tA = tb + 2 * (k);                                           \
    const int iAm = iA & 1023, iBm = iB & 1023;                            \
    float ncA, ncB, v2cB;                                                  \
    const float v2cA = (ZEROC) ? vA : (vA - c2vf[2 * (k)]);                \
    if (__builtin_amdgcn_readfirstlane(iB) & 0x8000) {                     \
      /* B overlaps A: strict sequential order */                          \
      ncA = check_msg(v2cA, sh);                                           \
      vn[iAm][g] = v2cA + ncA;                                             \
      const float vBr = vn[iBm][g]; /* re-gather after scatter A */        \
      v2cB = (ZEROC) ? vBr : (vBr - c2vf[2 * (k) + 1]);                    \
      ncB = check_msg(v2cB, sh);                                           \
      vn[iBm][g] = v2cB + ncB;                                             \
    } else {                                                               \
      v2cB = (ZEROC) ? vB : (vB - c2vf[2 * (k) + 1]);                      \
      ncA = check_msg(v2cA, sh);                                           \
      ncB = check_msg(v2cB, sh);                                           \
      vn[iAm][g] = v2cA + ncA;                                             \
      vn[iBm][g] = v2cB + ncB;                                             \
    }                                                                      \
    /* c2v traffic: uniform slot offset (SALU) + invariant lane offset */  \
    g_c2v[((unsigned)tA << 16) + lane] = ncA;                              \
    g_c2v[(((unsigned)tA + 1u) << 16) + lane] = ncB;                       \
    if (LOADC) {                                                           \
      c2vf[2 * (k)] = g_c2v[((unsigned)((tA + 8) & 511) << 16) + lane];    \
      c2vf[2 * (k) + 1] =                                                  \
          g_c2v[((unsigned)((tA + 9) & 511) << 16) + lane];                \
    }                                                                      \
    /* early gathers for next pair (see all scatters <= tB: no hazard) */  \
    vA = vn[iA1 & 1023][g];                                                \
    vB = vn[iB1 & 1023][g];                                                \
    iA = iA1;                                                              \
    iB = iB1;                                                              \
    iA1 = hp[((tA + 4) & 511) * WRc + j];                                  \
    iB1 = hp[((tA + 5) & 511) * WRc + j];                                  \
  }

#define PAIR4(Z, L) PAIR(0, Z, L) PAIR(1, Z, L) PAIR(2, Z, L) PAIR(3, Z, L)

__global__ __launch_bounds__(64) void ldpc_kernel(
    const float* __restrict__ llr, const int* __restrict__ H,
    const int* __restrict__ iters_p, const int* __restrict__ cn_order,
    float* __restrict__ out) {
  const int tid = threadIdx.x;
  const int g = tid >> 4;    // batch sub-slot within wave (0..3)
  const int j = tid & 15;    // edge position within check node
  const int sh = tid & 48;   // g*16, ballot slice shift
  const int b0 = blockIdx.x * 4;
  const unsigned lane = (unsigned)(b0 * 16 + tid);  // (b*WR + j), per-lane

  // [n][g] layout: bank = (4n+g)%32 -> the 4 groups occupy disjoint bank
  // quads; within-group conflicts are data-dependent (~2-way avg, cheap).
  __shared__ float vn[Nc][4];              // 16 KB
  __shared__ unsigned short hp[Mc * WRc];  // 16 KB, bit15 = overlap(s, s-1)

  for (int i = tid; i < 4 * Nc; i += 64) {
    const int gg = i >> 10, n = i & (Nc - 1);
    vn[n][gg] = llr[(size_t)(b0 + gg) * Nc + n];
  }
  for (int i = tid; i < Mc * WRc; i += 64)
    hp[i] = (unsigned short)H[cn_order[i >> 4] * WRc + (i & 15)];
  __syncthreads();

  // Precompute per-row overlap flags: bit15 of every entry of row s marks
  // overlap(row s, row s-1 mod 512). For odd s this is exactly the
  // intra-pair hazard used by PAIR. One-time (~3 us).
  {
    unsigned ov = 0;
    unsigned short prev[16], cur[16];
    const int s0 = tid * 8;
    const int sp0 = (s0 + Mc - 1) & (Mc - 1);
#pragma unroll
    for (int a = 0; a < 16; ++a) prev[a] = hp[sp0 * WRc + a];
    for (int r = 0; r < 8; ++r) {
      const int s = s0 + r;
#pragma unroll
      for (int a = 0; a < 16; ++a) cur[a] = hp[s * WRc + a];
      bool o = false;
#pragma unroll
      for (int a = 0; a < 16; ++a)
#pragma unroll
        for (int c = 0; c < 16; ++c) o |= (cur[a] == prev[c]);
      ov |= (o ? 1u : 0u) << r;
#pragma unroll
      for (int a = 0; a < 16; ++a) prev[a] = cur[a];
    }
    __syncthreads();
    for (int r = 0; r < 8; ++r)
      if ((ov >> r) & 1u) {
        const int s = tid * 8 + r;
        for (int a = 0; a < 16; ++a) hp[s * WRc + a] |= 0x8000;
      }
    __syncthreads();
  }

  const int sweeps = iters_p[0];

  // ---- pipeline prime: pair 0 = rows 0,1; next-pair idx = rows 2,3 ----
  int iA = hp[0 * WRc + j];
  int iB = hp[1 * WRc + j];
  int iA1 = hp[2 * WRc + j];
  int iB1 = hp[3 * WRc + j];
  float vA = vn[iA & 1023][g];
  float vB = vn[iB & 1023][g];
  float c2vf[8] = {0, 0, 0, 0, 0, 0, 0, 0};

  // Sweep 0 (c2v == 0): no prefetch until the last 4 pairs, which start
  // loading slots 0..7 (written at sweep-0 rows 0..7) for sweep 1.
  int tb = 0;
  for (; tb < Mc - 8; tb += 8) { PAIR4(1, 0) }
  { PAIR4(1, 1) }  // tb == 504
  // Main sweeps: prefetch depth 8 rows (= one unrolled iteration, static
  // c2vf indices -> registers).
  for (int sw = 1; sw < sweeps; ++sw) {
    for (tb = 0; tb < Mc; tb += 8) { PAIR4(0, 1) }
  }

  // Hard decision. Block = one wave: wave-synchronous, no barrier needed.
  for (int i = tid; i < 4 * Nc; i += 64) {
    const int gg = i >> 10, n = i & (Nc - 1);
    out[(size_t)(b0 + gg) * Nc + n] = (vn[n][gg] < 0.0f) ? 1.0f : 0.0f;
  }
}

extern "C" void kernel_launch(void* const* d_in, const int* in_sizes, int n_in,
                              void* d_out, int out_size, void* d_ws, size_t ws_size,
                              hipStream_t stream) {
  const float* llr = (const float*)d_in[0];
  const int* H = (const int*)d_in[1];
  const int* iters_p = (const int*)d_in[2];
  const int* cn_order = (const int*)d_in[3];
  float* out = (float*)d_out;
  ldpc_kernel<<<dim3(Bc / 4), dim3(64), 0, stream>>>(llr, H, iters_p, cn_order, out);
}